// Round 1
// baseline (363.075 us; speedup 1.0000x reference)
//
#include <hip/hip_runtime.h>
#include <hip/hip_bf16.h>

// CapsuleLayer dynamic routing, fully fused except squash.
// Key identity: b_r[b,j,i] = sum_k u_hat[b,j,i,k] * Vacc[b,j,k],
//   Vacc = sum of v from previous routing iterations.
// => u_hat is never materialized; only state is Vacc (256KB) + s (256KB) in ws.

#define B_TOT   128
#define J_CAPS  32
#define I_CAPS  1152
#define K_DIM   16
#define L_DIM   8

#define BGRP    16                    // batches per workgroup
#define NBG     (B_TOT / BGRP)        // 8
#define I_TILE  18                    // i's per workgroup
#define NSLICE  (I_CAPS / I_TILE)     // 64
#define WJ_STRIDE (I_CAPS * K_DIM * L_DIM)  // 147456 floats between j planes

template<int R>
__global__ __launch_bounds__(256, 2)
void caps_route(const float* __restrict__ x,     // [128,1152,8]
                const float* __restrict__ W,     // [32,1152,16,8]
                const float* __restrict__ Vacc,  // [128,32,16]
                float* __restrict__ s)           // [128,32,16] (pre-zeroed)
{
    const int tid = threadIdx.x;
    const int k   = tid & 15;         // capsule dim lane
    const int bl  = tid >> 4;         // local batch 0..15
    const int bg  = blockIdx.x / NSLICE;
    const int sl  = blockIdx.x % NSLICE;
    const int b   = bg * BGRP + bl;
    const int i0  = sl * I_TILE;

    __shared__ float xs[BGRP][I_TILE][L_DIM];   // 9 KB

    // cooperative load of x slice (contiguous per batch-row)
    for (int idx = tid; idx < BGRP * I_TILE * L_DIM; idx += 256) {
        int bb  = idx / (I_TILE * L_DIM);
        int rem = idx - bb * (I_TILE * L_DIM);
        int ii  = rem / L_DIM;
        int l   = rem - ii * L_DIM;
        xs[bb][ii][l] =
            x[((size_t)(bg * BGRP + bb) * I_CAPS + (i0 + ii)) * L_DIM + l];
    }
    __syncthreads();

    // V for this (b, k) across all j — register resident
    float Vr[J_CAPS];
    if (R > 0) {
        #pragma unroll
        for (int j = 0; j < J_CAPS; ++j)
            Vr[j] = Vacc[((size_t)b * J_CAPS + j) * K_DIM + k];
    }

    float sacc[J_CAPS];
    #pragma unroll
    for (int j = 0; j < J_CAPS; ++j) sacc[j] = 0.0f;

    // base pointer for this lane's k within W
    const float* Wk = W + (size_t)k * L_DIM;

    for (int ii = 0; ii < I_TILE; ++ii) {
        const int i = i0 + ii;
        const float4* xp = reinterpret_cast<const float4*>(&xs[bl][ii][0]);
        const float4 x0 = xp[0];
        const float4 x1 = xp[1];

        const float* Wi = Wk + (size_t)i * (K_DIM * L_DIM);

        // u_hat[b, j, i, k] for all j — fully unrolled so u[] stays in VGPRs
        float u[J_CAPS];
        #pragma unroll
        for (int j = 0; j < J_CAPS; ++j) {
            const float4* wj =
                reinterpret_cast<const float4*>(Wi + (size_t)j * WJ_STRIDE);
            const float4 w0 = wj[0];
            const float4 w1 = wj[1];
            u[j] = w0.x * x0.x + w0.y * x0.y + w0.z * x0.z + w0.w * x0.w
                 + w1.x * x1.x + w1.y * x1.y + w1.z * x1.z + w1.w * x1.w;
        }

        if (R == 0) {
            // b == 0 -> softmax over j is uniform 1/32
            #pragma unroll
            for (int j = 0; j < J_CAPS; ++j)
                sacc[j] += (1.0f / 32.0f) * u[j];
        } else {
            // b_raw[j] = sum_k u[j,k] * Vacc[j,k]  (reduce across 16 k-lanes)
            float braw[J_CAPS];
            #pragma unroll
            for (int j = 0; j < J_CAPS; ++j) {
                float p = u[j] * Vr[j];
                p += __shfl_xor(p, 1);
                p += __shfl_xor(p, 2);
                p += __shfl_xor(p, 4);
                p += __shfl_xor(p, 8);
                braw[j] = p;
            }
            // softmax over j (per-lane; every lane holds full b_raw[j])
            float m = braw[0];
            #pragma unroll
            for (int j = 1; j < J_CAPS; ++j) m = fmaxf(m, braw[j]);
            float denom = 0.0f;
            #pragma unroll
            for (int j = 0; j < J_CAPS; ++j) {
                braw[j] = __expf(braw[j] - m);
                denom += braw[j];
            }
            const float inv = 1.0f / denom;
            #pragma unroll
            for (int j = 0; j < J_CAPS; ++j)
                sacc[j] += braw[j] * inv * u[j];
        }
    }

    // flush partial s: each thread owns a unique (b,k) in this WG; only
    // cross-WG (i-slice) accumulation needs atomics.
    #pragma unroll
    for (int j = 0; j < J_CAPS; ++j)
        atomicAdd(&s[((size_t)b * J_CAPS + j) * K_DIM + k], sacc[j]);
}

template<bool FINAL>
__global__ __launch_bounds__(256)
void caps_squash(const float* __restrict__ s,
                 float* __restrict__ Vacc,
                 float* __restrict__ out)
{
    const int tid = blockIdx.x * 256 + threadIdx.x;   // 0..65535, k fastest
    const float sv = s[tid];
    float p = sv * sv;
    p += __shfl_xor(p, 1);
    p += __shfl_xor(p, 2);
    p += __shfl_xor(p, 4);
    p += __shfl_xor(p, 8);
    const float scale = p / ((1.0f + p) * sqrtf(p + 1e-7f));
    const float v = scale * sv;
    if (FINAL) out[tid] = v;
    else       Vacc[tid] += v;
}

extern "C" void kernel_launch(void* const* d_in, const int* in_sizes, int n_in,
                              void* d_out, int out_size, void* d_ws, size_t ws_size,
                              hipStream_t stream)
{
    const float* x = (const float*)d_in[0];   // [128,1152,8]
    const float* W = (const float*)d_in[1];   // [32,1152,16,8]
    float* out  = (float*)d_out;              // [128,32,16]
    float* Vacc = (float*)d_ws;               // 65536 floats
    float* s    = Vacc + 65536;               // 65536 floats

    const size_t SB = (size_t)65536 * sizeof(float);
    hipMemsetAsync(Vacc, 0, SB, stream);

    dim3 grid(NBG * NSLICE);   // 512 WGs
    dim3 blk(256);

    // r = 0 (uniform c)
    hipMemsetAsync(s, 0, SB, stream);
    caps_route<0><<<grid, blk, 0, stream>>>(x, W, Vacc, s);
    caps_squash<false><<<256, 256, 0, stream>>>(s, Vacc, out);

    // r = 1
    hipMemsetAsync(s, 0, SB, stream);
    caps_route<1><<<grid, blk, 0, stream>>>(x, W, Vacc, s);
    caps_squash<false><<<256, 256, 0, stream>>>(s, Vacc, out);

    // r = 2 (final -> d_out)
    hipMemsetAsync(s, 0, SB, stream);
    caps_route<2><<<grid, blk, 0, stream>>>(x, W, Vacc, s);
    caps_squash<true><<<256, 256, 0, stream>>>(s, Vacc, out);
}

// Round 2
// 341.237 us; speedup vs baseline: 1.0640x; 1.0640x over previous
//
#include <hip/hip_runtime.h>
#include <hip/hip_bf16.h>
#include <stdint.h>

// CapsuleLayer dynamic routing v2.
// b_r[b,j,i] = sum_k u_hat[b,j,i,k] * Vacc[b,j,k]  (Vacc = sum of prior v's)
// => u_hat recomputed in registers each pass; W tiles staged through LDS
//    (global_load_lds, double-buffered, XOR-swizzled against bank conflicts).

#define B_TOT   128
#define J_CAPS  32
#define I_CAPS  1152
#define K_DIM   16
#define L_DIM   8

#define BGRP    16                    // batches per WG
#define NBG     (B_TOT / BGRP)        // 8
#define I_TILE  12                    // i's per WG
#define NSLICE  (I_CAPS / I_TILE)     // 96  -> grid 768 = 3 WG/CU exact
#define XS_STRIDE 100                 // 96 floats + 4 pad (bank spread)
#define WJ_STRIDE (I_CAPS * 128)      // floats between j planes: 147456

template<int R>
__global__ __launch_bounds__(256, 3)
void caps_route(const float* __restrict__ x,     // [128,1152,8]
                const float* __restrict__ W,     // [32,1152,16,8]
                const float* __restrict__ Vacc,  // [128,32,16]
                float* __restrict__ s)           // [128,32,16] zeroed
{
    __shared__ float Wb[2][4096];            // 2 x 16KB, linear j-major
    __shared__ float xs[BGRP * XS_STRIDE];   // 6.4KB

    const int tid  = threadIdx.x;
    const int lane = tid & 63;
    const int w    = tid >> 6;               // wave id 0..3
    const int k    = tid & 15;
    const int bl   = tid >> 4;               // local batch 0..15
    const int bg   = blockIdx.x / NSLICE;
    const int sl   = blockIdx.x % NSLICE;
    const int b    = bg * BGRP + bl;
    const int i0   = sl * I_TILE;

    // ---- stage x slice: 16 b-rows x 96 contiguous floats ----
    for (int c = tid; c < BGRP * 24; c += 256) {
        int bb = c / 24;
        int cc = c - bb * 24;
        float4 v = *reinterpret_cast<const float4*>(
            x + ((size_t)(bg * BGRP + bb) * I_CAPS + i0) * L_DIM + cc * 4);
        *reinterpret_cast<float4*>(xs + bb * XS_STRIDE + cc * 4) = v;
    }

    // ---- staging constants: LDS linear granule p_in <- global granule g ----
    // self-inverse XOR swizzle: g = p ^ ((p>>3)&3)  (rows of 8 granules)
    const int p_in  = lane & 31;             // 16B granule within 512B j-block
    const int j_off = lane >> 5;             // which j of the pair
    const int g     = p_in ^ ((p_in >> 3) & 3);

    // read-side swizzled positions for this lane's (k): source granules 2k,2k+1
    const int r_   = (k >> 2) & 3;
    const int pos0 = (2 * k) ^ r_;
    const int pos1 = pos0 ^ 1;

    // stage one i-tile (16KB = 16 pair-blocks of 1KB; 4 waves x 4 instrs)
    auto stage = [&](int bufsel, int ig) {
        #pragma unroll
        for (int t = 0; t < 4; ++t) {
            const int p = w * 4 + t;                  // pair-block 0..15
            const int j = 2 * p + j_off;
            const float* src = W + (size_t)j * WJ_STRIDE + (size_t)ig * 128 + g * 4;
            __builtin_amdgcn_global_load_lds(
                (const __attribute__((address_space(1))) uint32_t*)src,
                (__attribute__((address_space(3))) uint32_t*)&Wb[bufsel][p * 256],
                16, 0, 0);
        }
    };

    stage(0, i0);
    __syncthreads();   // xs + first W tile ready (barrier drains vmcnt)

    float Vr[J_CAPS];
    if (R > 0) {
        #pragma unroll
        for (int j = 0; j < J_CAPS; ++j)
            Vr[j] = Vacc[((size_t)b * J_CAPS + j) * K_DIM + k] * 1.44269504f;
    }

    float sacc[J_CAPS];
    #pragma unroll
    for (int j = 0; j < J_CAPS; ++j) sacc[j] = 0.0f;

    for (int ii = 0; ii < I_TILE; ++ii) {
        const int cur = ii & 1;
        if (ii + 1 < I_TILE) stage(cur ^ 1, i0 + ii + 1);   // prefetch next

        const float4 x0 = *reinterpret_cast<const float4*>(xs + bl * XS_STRIDE + ii * 8);
        const float4 x1 = *reinterpret_cast<const float4*>(xs + bl * XS_STRIDE + ii * 8 + 4);

        const float* A0 = &Wb[cur][pos0 * 4];
        const float* A1 = &Wb[cur][pos1 * 4];

        float u[J_CAPS];
        #pragma unroll
        for (int j = 0; j < J_CAPS; ++j) {
            const float4 w0 = *reinterpret_cast<const float4*>(A0 + j * 128);
            const float4 w1 = *reinterpret_cast<const float4*>(A1 + j * 128);
            u[j] = w0.x * x0.x + w0.y * x0.y + w0.z * x0.z + w0.w * x0.w
                 + w1.x * x1.x + w1.y * x1.y + w1.z * x1.z + w1.w * x1.w;
        }

        if (R == 0) {
            #pragma unroll
            for (int j = 0; j < J_CAPS; ++j)
                sacc[j] += (1.0f / 32.0f) * u[j];
        } else {
            float braw[J_CAPS];
            #pragma unroll
            for (int j = 0; j < J_CAPS; ++j) {
                float t = u[j] * Vr[j];          // log2-domain (Vr prescaled)
                t += __shfl_xor(t, 1);
                t += __shfl_xor(t, 2);
                t += __shfl_xor(t, 4);
                t += __shfl_xor(t, 8);
                braw[j] = t;
            }
            float m = braw[0];
            #pragma unroll
            for (int j = 1; j < J_CAPS; ++j) m = fmaxf(m, braw[j]);
            float denom = 0.0f;
            #pragma unroll
            for (int j = 0; j < J_CAPS; ++j) {
                braw[j] = exp2f(braw[j] - m);    // v_exp_f32
                denom  += braw[j];
            }
            const float inv = __builtin_amdgcn_rcpf(denom);
            #pragma unroll
            for (int j = 0; j < J_CAPS; ++j)
                sacc[j] += braw[j] * inv * u[j];
        }
        __syncthreads();   // prefetch landed + all reads of cur done
    }

    #pragma unroll
    for (int j = 0; j < J_CAPS; ++j)
        atomicAdd(&s[((size_t)b * J_CAPS + j) * K_DIM + k], sacc[j]);
}

// MODE 0: Vacc = v, zero s;  MODE 1: Vacc += v, zero s;  MODE 2: out = v
template<int MODE>
__global__ __launch_bounds__(256)
void caps_squash(float* __restrict__ s,
                 float* __restrict__ Vacc,
                 float* __restrict__ out)
{
    const int t = blockIdx.x * 256 + threadIdx.x;   // (b,j,k), k fastest
    const float sv = s[t];
    float p = sv * sv;
    p += __shfl_xor(p, 1);
    p += __shfl_xor(p, 2);
    p += __shfl_xor(p, 4);
    p += __shfl_xor(p, 8);
    const float scale = p / ((1.0f + p) * sqrtf(p + 1e-7f));
    const float v = scale * sv;
    if (MODE == 0)      { Vacc[t] = v;  s[t] = 0.0f; }
    else if (MODE == 1) { Vacc[t] += v; s[t] = 0.0f; }
    else                { out[t] = v; }
}

extern "C" void kernel_launch(void* const* d_in, const int* in_sizes, int n_in,
                              void* d_out, int out_size, void* d_ws, size_t ws_size,
                              hipStream_t stream)
{
    const float* x = (const float*)d_in[0];   // [128,1152,8]
    const float* W = (const float*)d_in[1];   // [32,1152,16,8]
    float* out  = (float*)d_out;              // [128,32,16]
    float* Vacc = (float*)d_ws;               // 65536 floats
    float* s    = Vacc + 65536;               // 65536 floats

    hipMemsetAsync(s, 0, (size_t)65536 * sizeof(float), stream);

    dim3 grid(NBG * NSLICE);   // 768 WGs = 3/CU exact
    dim3 blk(256);

    caps_route<0><<<grid, blk, 0, stream>>>(x, W, Vacc, s);
    caps_squash<0><<<256, 256, 0, stream>>>(s, Vacc, out);

    caps_route<1><<<grid, blk, 0, stream>>>(x, W, Vacc, s);
    caps_squash<1><<<256, 256, 0, stream>>>(s, Vacc, out);

    caps_route<2><<<grid, blk, 0, stream>>>(x, W, Vacc, s);
    caps_squash<2><<<256, 256, 0, stream>>>(s, Vacc, out);
}